// Round 2
// baseline (1113.601 us; speedup 1.0000x reference)
//
#include <hip/hip_runtime.h>
#include <hip/hip_bf16.h>

#define Bb 4
#define Nn 1024
#define Dd 512
#define Hh 8
#define Ee 5
#define HDd 64
#define TM 8

// ---------- Kernel 0: normalize node_mask (int32 or byte-bool) -> int mw[4096], anyB[4] ----------
__global__ __launch_bounds__(256) void prep_mask(const void* __restrict__ msk,
                                                 int* __restrict__ mw,
                                                 int* __restrict__ anyB) {
    __shared__ int notint;
    __shared__ int ab[Bb];
    const int tid = threadIdx.x;
    if (tid == 0) notint = 0;
    if (tid < Bb) ab[tid] = 0;
    __syncthreads();
    // Scan only the first 4096 bytes (safe under both interpretations).
    const unsigned int* wp = (const unsigned int*)msk;
    int bad = 0;
    for (int i = tid; i < 1024; i += 256) bad |= (wp[i] > 1u);
    if (bad) atomicOr(&notint, 1);
    __syncthreads();
    const int isbyte = notint;
    const unsigned char* bp = (const unsigned char*)msk;
    for (int i = tid; i < Bb * Nn; i += 256) {
        const int v = isbyte ? (bp[i] != 0) : (wp[i] != 0);
        mw[i] = v;
        if (v) atomicOr(&ab[i >> 10], 1);
    }
    __syncthreads();
    if (tid < Bb) anyB[tid] = ab[tid];
}

// ---------- Kernel A: qkv = x @ w_qkv^T, scatter to q,k,v (b,h,n,d) fp32 ----------
__global__ __launch_bounds__(256) void qkv_proj(const float* __restrict__ x,
                                                const float* __restrict__ w,
                                                float* __restrict__ q,
                                                float* __restrict__ k,
                                                float* __restrict__ v) {
    __shared__ float4 xs[TM][Dd / 4];
    const int r0 = blockIdx.y * TM;                 // row block (same batch: TM | Nn)
    const int c = blockIdx.x * 256 + threadIdx.x;   // 0..1535
    for (int t = threadIdx.x; t < TM * (Dd / 4); t += 256) {
        const int rr = t / (Dd / 4), kk = t % (Dd / 4);
        xs[rr][kk] = ((const float4*)(x + (size_t)(r0 + rr) * Dd))[kk];
    }
    __syncthreads();
    const float4* wr = (const float4*)(w + (size_t)c * Dd);
    float acc[TM];
    #pragma unroll
    for (int r = 0; r < TM; r++) acc[r] = 0.f;
    for (int kk = 0; kk < Dd / 4; kk++) {
        const float4 wv = wr[kk];
        #pragma unroll
        for (int r = 0; r < TM; r++) {
            const float4 xv = xs[r][kk];
            acc[r] = fmaf(xv.x, wv.x, fmaf(xv.y, wv.y, fmaf(xv.z, wv.z, fmaf(xv.w, wv.w, acc[r]))));
        }
    }
    const int s = c >> 9, hd = c & 511, h = hd >> 6, d = hd & 63;
    const int b = r0 >> 10;
    float* dst = (s == 0) ? q : (s == 1) ? k : v;
    #pragma unroll
    for (int r = 0; r < TM; r++) {
        const int n = (r0 + r) & (Nn - 1);
        dst[((((size_t)b * Hh + h) * Nn) + n) * HDd + d] = acc[r];
    }
}

// ---------- Kernel B: attention, one block per (b, i), all 8 heads ----------
__global__ __launch_bounds__(256) void attn_kernel(const float* __restrict__ q,
                                                   const float* __restrict__ kg,
                                                   const float* __restrict__ vg,
                                                   const float* __restrict__ ef,
                                                   const int* __restrict__ mw,
                                                   const int* __restrict__ anyB,
                                                   const float* __restrict__ wep,
                                                   const float* __restrict__ weg,
                                                   const float* __restrict__ beg,
                                                   float* __restrict__ aout) {
    __shared__ float sc[Hh][Nn];       // 32 KB
    __shared__ float qs[Hh][HDd];      // 2 KB
    __shared__ float weps[Hh][Ee], wegs[Hh][Ee], begs[Hh];
    const int tid = threadIdx.x;
    const int bi = blockIdx.x;
    const int b = bi >> 10, i = bi & (Nn - 1);

    if (tid < Hh * Ee) {
        weps[tid / Ee][tid % Ee] = wep[tid];
        wegs[tid / Ee][tid % Ee] = weg[tid];
    }
    if (tid < Hh) begs[tid] = beg[tid];
    for (int t = tid; t < Hh * HDd; t += 256) {
        const int h = t >> 6, d = t & 63;
        qs[h][d] = q[((((size_t)b * Hh + h) * Nn) + i) * HDd + d];
    }
    __syncthreads();

    const int rowvalid = (mw[b * Nn + i] != 0) && (anyB[b] != 0);
    const float scale = 0.125f;  // HD^-0.5

    if (!rowvalid) {
        // reference: invalid row -> scores = 0 -> uniform softmax over ALL columns
        for (int j = tid; j < Nn; j += 256)
            for (int h = 0; h < Hh; h++) sc[h][j] = 0.f;
    } else {
        for (int j = tid; j < Nn; j += 256) {
            if (!mw[b * Nn + j]) {
                for (int h = 0; h < Hh; h++) sc[h][j] = -__builtin_inff();
                continue;
            }
            const float* ep = ef + (((size_t)(b * Nn + i)) * Nn + j) * Ee;
            const float e0 = ep[0], e1 = ep[1], e2 = ep[2], e3 = ep[3], e4 = ep[4];
            const float4* kb = (const float4*)(kg + (((size_t)b * Hh) * Nn + j) * HDd);
            #pragma unroll 2
            for (int h = 0; h < Hh; h++) {
                const float4* kr = kb + (size_t)h * Nn * (HDd / 4);
                float dot = 0.f;
                #pragma unroll
                for (int d = 0; d < HDd / 4; d++) {
                    const float4 kv = kr[d];
                    dot = fmaf(qs[h][4 * d + 0], kv.x, dot);
                    dot = fmaf(qs[h][4 * d + 1], kv.y, dot);
                    dot = fmaf(qs[h][4 * d + 2], kv.z, dot);
                    dot = fmaf(qs[h][4 * d + 3], kv.w, dot);
                }
                const float bias = e0 * weps[h][0] + e1 * weps[h][1] + e2 * weps[h][2] +
                                   e3 * weps[h][3] + e4 * weps[h][4];
                const float gv = e0 * wegs[h][0] + e1 * wegs[h][1] + e2 * wegs[h][2] +
                                 e3 * wegs[h][3] + e4 * wegs[h][4] + begs[h];
                const float gate = 1.f / (1.f + __expf(-gv));
                sc[h][j] = dot * scale + gate * bias;
            }
        }
    }
    __syncthreads();

    // softmax: wave wv handles heads wv and wv+4
    const int wv = tid >> 6, lane = tid & 63;
    for (int h = wv; h < Hh; h += 4) {
        float m = -__builtin_inff();
        for (int j = lane; j < Nn; j += 64) m = fmaxf(m, sc[h][j]);
        #pragma unroll
        for (int off = 32; off > 0; off >>= 1) m = fmaxf(m, __shfl_xor(m, off));
        float s = 0.f;
        for (int j = lane; j < Nn; j += 64) {
            const float e = __expf(sc[h][j] - m);
            sc[h][j] = e;
            s += e;
        }
        #pragma unroll
        for (int off = 32; off > 0; off >>= 1) s += __shfl_xor(s, off);
        const float inv = 1.f / s;
        for (int j = lane; j < Nn; j += 64) sc[h][j] *= inv;
    }
    __syncthreads();

    // PV: 512 outputs, 2 per thread
    for (int o = tid; o < Dd; o += 256) {
        const int h = o >> 6, d = o & 63;
        const float* vb = vg + (((size_t)b * Hh + h) * Nn) * HDd + d;
        float acc = 0.f;
        #pragma unroll 4
        for (int j = 0; j < Nn; j++) acc = fmaf(sc[h][j], vb[(size_t)j * HDd], acc);
        aout[((size_t)b * Nn + i) * Dd + o] = acc;
    }
}

// ---------- Kernel C: out = attn_out @ w_proj^T + b_proj ----------
__global__ __launch_bounds__(256) void out_proj(const float* __restrict__ a,
                                                const float* __restrict__ w,
                                                const float* __restrict__ bias,
                                                float* __restrict__ out) {
    __shared__ float4 xs[TM][Dd / 4];
    const int r0 = blockIdx.y * TM;
    const int c = blockIdx.x * 256 + threadIdx.x;  // 0..511
    for (int t = threadIdx.x; t < TM * (Dd / 4); t += 256) {
        const int rr = t / (Dd / 4), kk = t % (Dd / 4);
        xs[rr][kk] = ((const float4*)(a + (size_t)(r0 + rr) * Dd))[kk];
    }
    __syncthreads();
    const float4* wr = (const float4*)(w + (size_t)c * Dd);
    float acc[TM];
    #pragma unroll
    for (int r = 0; r < TM; r++) acc[r] = 0.f;
    for (int kk = 0; kk < Dd / 4; kk++) {
        const float4 wv = wr[kk];
        #pragma unroll
        for (int r = 0; r < TM; r++) {
            const float4 xv = xs[r][kk];
            acc[r] = fmaf(xv.x, wv.x, fmaf(xv.y, wv.y, fmaf(xv.z, wv.z, fmaf(xv.w, wv.w, acc[r]))));
        }
    }
    const float bc = bias[c];
    #pragma unroll
    for (int r = 0; r < TM; r++) out[(size_t)(r0 + r) * Dd + c] = acc[r] + bc;
}

extern "C" void kernel_launch(void* const* d_in, const int* in_sizes, int n_in,
                              void* d_out, int out_size, void* d_ws, size_t ws_size,
                              hipStream_t stream) {
    const float* x    = (const float*)d_in[0];
    const float* ef   = (const float*)d_in[1];
    const void*  msk  = d_in[2];
    const float* wqkv = (const float*)d_in[3];
    const float* wep  = (const float*)d_in[4];
    const float* weg  = (const float*)d_in[5];
    const float* beg  = (const float*)d_in[6];
    const float* wpj  = (const float*)d_in[7];
    const float* bpj  = (const float*)d_in[8];
    float* out = (float*)d_out;

    int* mw   = (int*)d_ws;            // 4096 ints
    int* anyB = mw + Bb * Nn;          // 4 ints (pad to 16)
    float* qws = (float*)(anyB + 16);
    const size_t per = (size_t)Bb * Hh * Nn * HDd;  // 2,097,152
    float* kws = qws + per;
    float* vws = kws + per;
    float* aws = vws + per;            // B*N*D fp32

    prep_mask<<<1, 256, 0, stream>>>(msk, mw, anyB);
    qkv_proj<<<dim3(6, Bb * Nn / TM), 256, 0, stream>>>(x, wqkv, qws, kws, vws);
    attn_kernel<<<dim3(Bb * Nn), 256, 0, stream>>>(qws, kws, vws, ef, mw, anyB,
                                                   wep, weg, beg, aws);
    out_proj<<<dim3(2, Bb * Nn / TM), 256, 0, stream>>>(aws, wpj, bpj, out);
}

// Round 3
// 650.049 us; speedup vs baseline: 1.7131x; 1.7131x over previous
//
#include <hip/hip_runtime.h>
#include <hip/hip_bf16.h>

#define Bb 4
#define Nn 1024
#define Dd 512
#define Hh 8
#define Ee 5
#define HDd 64
#define TI 64
#define TJ 64

// ---------- Kernel 0: normalize node_mask (int32 or byte-bool) -> int mw[4096], anyB[4] ----------
__global__ __launch_bounds__(256) void prep_mask(const void* __restrict__ msk,
                                                 int* __restrict__ mw,
                                                 int* __restrict__ anyB) {
    __shared__ int notint;
    __shared__ int ab[Bb];
    const int tid = threadIdx.x;
    if (tid == 0) notint = 0;
    if (tid < Bb) ab[tid] = 0;
    __syncthreads();
    const unsigned int* wp = (const unsigned int*)msk;
    int bad = 0;
    for (int i = tid; i < 1024; i += 256) bad |= (wp[i] > 1u);
    if (bad) atomicOr(&notint, 1);
    __syncthreads();
    const int isbyte = notint;
    const unsigned char* bp = (const unsigned char*)msk;
    for (int i = tid; i < Bb * Nn; i += 256) {
        const int v = isbyte ? (bp[i] != 0) : (wp[i] != 0);
        mw[i] = v;
        if (v) atomicOr(&ab[i >> 10], 1);
    }
    __syncthreads();
    if (tid < Bb) anyB[tid] = ab[tid];
}

// ---------- Kernel A: qkv = x @ w_qkv^T -> q,k,v (b,h,n,d) fp32. 16 rows x 2 cols/thread ----------
__global__ __launch_bounds__(256) void qkv_proj(const float* __restrict__ x,
                                                const float* __restrict__ w,
                                                float* __restrict__ q,
                                                float* __restrict__ k,
                                                float* __restrict__ v) {
    __shared__ float4 xs[16 * 128];
    const int tid = threadIdx.x;
    const int r0 = blockIdx.y * 16;
    const int c0 = blockIdx.x * 512 + tid;          // col0; col1 = c0 + 256
    for (int u = tid; u < 16 * 128; u += 256)
        xs[u] = ((const float4*)x)[(size_t)r0 * 128 + u];
    __syncthreads();
    const float4* w0 = (const float4*)w + (size_t)c0 * 128;
    const float4* w1 = w0 + 256 * 128;
    float a0[16], a1[16];
    #pragma unroll
    for (int r = 0; r < 16; r++) { a0[r] = 0.f; a1[r] = 0.f; }
    for (int kk = 0; kk < 128; kk++) {
        const float4 wv0 = w0[kk], wv1 = w1[kk];
        #pragma unroll
        for (int r = 0; r < 16; r++) {
            const float4 xv = xs[r * 128 + kk];
            a0[r] = fmaf(xv.x, wv0.x, fmaf(xv.y, wv0.y, fmaf(xv.z, wv0.z, fmaf(xv.w, wv0.w, a0[r]))));
            a1[r] = fmaf(xv.x, wv1.x, fmaf(xv.y, wv1.y, fmaf(xv.z, wv1.z, fmaf(xv.w, wv1.w, a1[r]))));
        }
    }
    const int b = r0 >> 10;
    #pragma unroll 2
    for (int cc = 0; cc < 2; cc++) {
        const int c = c0 + cc * 256;
        const int s = c >> 9, hd = c & 511, h = hd >> 6, d = hd & 63;
        float* dst = (s == 0) ? q : (s == 1) ? k : v;
        float* base = dst + ((((size_t)b * Hh + h) * Nn)) * HDd + d;
        #pragma unroll
        for (int r = 0; r < 16; r++) {
            const int n = (r0 + r) & (Nn - 1);
            base[(size_t)n * HDd] = cc ? a1[r] : a0[r];
        }
    }
}

// ---------- Kernel B: flash attention. Block = (i-tile 64, h, b). 256 thr, 4x4 micro ----------
__global__ __launch_bounds__(256) void attn_flash(const float* __restrict__ qg,
                                                  const float* __restrict__ kg,
                                                  const float* __restrict__ vg,
                                                  const float* __restrict__ ef,
                                                  const int* __restrict__ mw,
                                                  const int* __restrict__ anyB,
                                                  const float* __restrict__ wep,
                                                  const float* __restrict__ weg,
                                                  const float* __restrict__ beg,
                                                  float* __restrict__ aout) {
    // 64 KB total LDS: QT/KT transposed [kk][row] f4-chunks; Vs/Ps row-major.
    __shared__ float4 QT[16 * 64];   // QT[kk*64 + i]  = Q[i][4kk..]
    __shared__ float4 KT[16 * 64];   // KT[kk*64 + j]  = K[j][4kk..]
    __shared__ float4 Vs[64 * 16];   // Vs[j*16 + d4]  = V[j][4d4..]
    __shared__ float4 Ps[64 * 16];   // Ps[i*16 + j4]  = P[i][4j4..]

    const int tid = threadIdx.x;
    const int tc = tid & 15, tr = tid >> 4;
    const int i0 = blockIdx.x * TI;
    const int h  = blockIdx.y;
    const int b  = blockIdx.z;

    const float wp0 = wep[h*Ee+0], wp1 = wep[h*Ee+1], wp2 = wep[h*Ee+2],
                wp3 = wep[h*Ee+3], wp4 = wep[h*Ee+4];
    const float wg0 = weg[h*Ee+0], wg1 = weg[h*Ee+1], wg2 = weg[h*Ee+2],
                wg3 = weg[h*Ee+3], wg4 = weg[h*Ee+4];
    const float bgs = beg[h];

    const float4* qg4 = (const float4*)(qg + ((((size_t)b * Hh + h) * Nn) + i0) * HDd);
    const float4* kg4 = (const float4*)(kg + (((size_t)b * Hh + h) * Nn) * HDd);
    const float4* vg4 = (const float4*)(vg + (((size_t)b * Hh + h) * Nn) * HDd);

    // Q tile -> QT (transposed write, once)
    for (int u = tid; u < TI * 16; u += 256) {
        const int r = u >> 4, c = u & 15;
        QT[c * 64 + r] = qg4[u];
    }

    const int anyb = anyB[b];
    int iglob[4], rv[4];
    #pragma unroll
    for (int ri = 0; ri < 4; ri++) {
        iglob[ri] = i0 + 4 * tr + ri;
        rv[ri] = anyb && mw[b * Nn + iglob[ri]];
    }
    float m_[4], l_[4];
    float4 O4[4];
    #pragma unroll
    for (int ri = 0; ri < 4; ri++) {
        m_[ri] = -1e30f; l_[ri] = 0.f;
        O4[ri].x = O4[ri].y = O4[ri].z = O4[ri].w = 0.f;
    }

    for (int jt = 0; jt < Nn / TJ; jt++) {
        const int j0 = jt * TJ;
        __syncthreads();   // prev tile fully consumed (and Q visible on jt=0 after next barrier)
        for (int u = tid; u < TJ * 16; u += 256) {
            const int r = u >> 4, c = u & 15;
            KT[c * 64 + r] = kg4[(j0 + r) * 16 + c];
            Vs[r * 16 + c] = vg4[(j0 + r) * 16 + c];
        }
        __syncthreads();

        int mj[4];
        #pragma unroll
        for (int jc = 0; jc < 4; jc++) mj[jc] = mw[b * Nn + j0 + tc + 16 * jc];

        float s[4][4];
        #pragma unroll
        for (int ri = 0; ri < 4; ri++)
            #pragma unroll
            for (int jc = 0; jc < 4; jc++) s[ri][jc] = 0.f;

        #pragma unroll 4
        for (int kk = 0; kk < 16; kk++) {
            float4 qf[4], kf[4];
            #pragma unroll
            for (int ri = 0; ri < 4; ri++) qf[ri] = QT[kk * 64 + 4 * tr + ri];
            #pragma unroll
            for (int jc = 0; jc < 4; jc++) kf[jc] = KT[kk * 64 + tc + 16 * jc];
            #pragma unroll
            for (int ri = 0; ri < 4; ri++)
                #pragma unroll
                for (int jc = 0; jc < 4; jc++)
                    s[ri][jc] = fmaf(qf[ri].x, kf[jc].x,
                                fmaf(qf[ri].y, kf[jc].y,
                                fmaf(qf[ri].z, kf[jc].z,
                                fmaf(qf[ri].w, kf[jc].w, s[ri][jc]))));
        }

        // gate/bias + masking semantics
        #pragma unroll
        for (int ri = 0; ri < 4; ri++) {
            #pragma unroll
            for (int jc = 0; jc < 4; jc++) {
                float sv;
                if (!rv[ri]) {
                    sv = 0.f;                      // invalid row -> uniform softmax
                } else if (!mj[jc]) {
                    sv = -1e30f;                   // masked column
                } else {
                    const float* ep = ef + (((size_t)(b * Nn + iglob[ri]) * Nn) + j0 + tc + 16 * jc) * Ee;
                    const float e0 = ep[0], e1 = ep[1], e2 = ep[2], e3 = ep[3], e4 = ep[4];
                    const float bias = fmaf(e0, wp0, fmaf(e1, wp1, fmaf(e2, wp2, fmaf(e3, wp3, e4 * wp4))));
                    const float gv = fmaf(e0, wg0, fmaf(e1, wg1, fmaf(e2, wg2, fmaf(e3, wg3, fmaf(e4, wg4, bgs)))));
                    const float gate = 1.f / (1.f + __expf(-gv));
                    sv = fmaf(s[ri][jc], 0.125f, gate * bias);
                }
                s[ri][jc] = sv;
            }
        }

        // online softmax update (16 lanes per row-group share a row set)
        #pragma unroll
        for (int ri = 0; ri < 4; ri++) {
            float tmax = fmaxf(fmaxf(s[ri][0], s[ri][1]), fmaxf(s[ri][2], s[ri][3]));
            tmax = fmaxf(tmax, __shfl_xor(tmax, 1));
            tmax = fmaxf(tmax, __shfl_xor(tmax, 2));
            tmax = fmaxf(tmax, __shfl_xor(tmax, 4));
            tmax = fmaxf(tmax, __shfl_xor(tmax, 8));
            const float mnew = fmaxf(m_[ri], tmax);
            const float alpha = __expf(m_[ri] - mnew);
            float p[4], ps = 0.f;
            #pragma unroll
            for (int jc = 0; jc < 4; jc++) { p[jc] = __expf(s[ri][jc] - mnew); ps += p[jc]; }
            ps += __shfl_xor(ps, 1);
            ps += __shfl_xor(ps, 2);
            ps += __shfl_xor(ps, 4);
            ps += __shfl_xor(ps, 8);
            m_[ri] = mnew;
            l_[ri] = l_[ri] * alpha + ps;
            O4[ri].x *= alpha; O4[ri].y *= alpha; O4[ri].z *= alpha; O4[ri].w *= alpha;
            float* Prow = (float*)&Ps[(4 * tr + ri) * 16];
            #pragma unroll
            for (int jc = 0; jc < 4; jc++) Prow[tc + 16 * jc] = p[jc];
        }
        __syncthreads();

        // PV: O[i][4tc..] += P[i][j] * V[j][4tc..]
        #pragma unroll 2
        for (int jq = 0; jq < 16; jq++) {
            float4 pr[4], vv[4];
            #pragma unroll
            for (int ri = 0; ri < 4; ri++) pr[ri] = Ps[(4 * tr + ri) * 16 + jq];
            #pragma unroll
            for (int u = 0; u < 4; u++) vv[u] = Vs[(4 * jq + u) * 16 + tc];
            #pragma unroll
            for (int ri = 0; ri < 4; ri++) {
                O4[ri].x = fmaf(pr[ri].x, vv[0].x, fmaf(pr[ri].y, vv[1].x, fmaf(pr[ri].z, vv[2].x, fmaf(pr[ri].w, vv[3].x, O4[ri].x))));
                O4[ri].y = fmaf(pr[ri].x, vv[0].y, fmaf(pr[ri].y, vv[1].y, fmaf(pr[ri].z, vv[2].y, fmaf(pr[ri].w, vv[3].y, O4[ri].y))));
                O4[ri].z = fmaf(pr[ri].x, vv[0].z, fmaf(pr[ri].y, vv[1].z, fmaf(pr[ri].z, vv[2].z, fmaf(pr[ri].w, vv[3].z, O4[ri].z))));
                O4[ri].w = fmaf(pr[ri].x, vv[0].w, fmaf(pr[ri].y, vv[1].w, fmaf(pr[ri].z, vv[2].w, fmaf(pr[ri].w, vv[3].w, O4[ri].w))));
            }
        }
    }

    #pragma unroll
    for (int ri = 0; ri < 4; ri++) {
        const float inv = 1.f / l_[ri];
        float4 o;
        o.x = O4[ri].x * inv; o.y = O4[ri].y * inv; o.z = O4[ri].z * inv; o.w = O4[ri].w * inv;
        ((float4*)(aout + ((size_t)(b * Nn + iglob[ri])) * Dd + h * HDd))[tc] = o;
    }
}

// ---------- Kernel C: out = a @ w_proj^T + b_proj. 16 rows x 2 cols/thread ----------
__global__ __launch_bounds__(256) void out_proj(const float* __restrict__ a,
                                                const float* __restrict__ w,
                                                const float* __restrict__ bias,
                                                float* __restrict__ out) {
    __shared__ float4 xs[16 * 128];
    const int tid = threadIdx.x;
    const int r0 = blockIdx.y * 16;
    const int c0 = tid;                              // col1 = c0 + 256
    for (int u = tid; u < 16 * 128; u += 256)
        xs[u] = ((const float4*)a)[(size_t)r0 * 128 + u];
    __syncthreads();
    const float4* w0 = (const float4*)w + (size_t)c0 * 128;
    const float4* w1 = w0 + 256 * 128;
    float a0[16], a1[16];
    #pragma unroll
    for (int r = 0; r < 16; r++) { a0[r] = 0.f; a1[r] = 0.f; }
    for (int kk = 0; kk < 128; kk++) {
        const float4 wv0 = w0[kk], wv1 = w1[kk];
        #pragma unroll
        for (int r = 0; r < 16; r++) {
            const float4 xv = xs[r * 128 + kk];
            a0[r] = fmaf(xv.x, wv0.x, fmaf(xv.y, wv0.y, fmaf(xv.z, wv0.z, fmaf(xv.w, wv0.w, a0[r]))));
            a1[r] = fmaf(xv.x, wv1.x, fmaf(xv.y, wv1.y, fmaf(xv.z, wv1.z, fmaf(xv.w, wv1.w, a1[r]))));
        }
    }
    const float b0 = bias[c0], b1 = bias[c0 + 256];
    #pragma unroll
    for (int r = 0; r < 16; r++) {
        out[(size_t)(r0 + r) * Dd + c0]       = a0[r] + b0;
        out[(size_t)(r0 + r) * Dd + c0 + 256] = a1[r] + b1;
    }
}

extern "C" void kernel_launch(void* const* d_in, const int* in_sizes, int n_in,
                              void* d_out, int out_size, void* d_ws, size_t ws_size,
                              hipStream_t stream) {
    const float* x    = (const float*)d_in[0];
    const float* ef   = (const float*)d_in[1];
    const void*  msk  = d_in[2];
    const float* wqkv = (const float*)d_in[3];
    const float* wep  = (const float*)d_in[4];
    const float* weg  = (const float*)d_in[5];
    const float* beg  = (const float*)d_in[6];
    const float* wpj  = (const float*)d_in[7];
    const float* bpj  = (const float*)d_in[8];
    float* out = (float*)d_out;

    int* mw   = (int*)d_ws;            // 4096 ints
    int* anyB = mw + Bb * Nn;          // 4 ints (pad to 16)
    float* qws = (float*)(anyB + 16);
    const size_t per = (size_t)Bb * Hh * Nn * HDd;  // 2,097,152
    float* kws = qws + per;
    float* vws = kws + per;
    float* aws = vws + per;            // B*N*D fp32

    prep_mask<<<1, 256, 0, stream>>>(msk, mw, anyB);
    qkv_proj<<<dim3(3, Bb * Nn / 16), 256, 0, stream>>>(x, wqkv, qws, kws, vws);
    attn_flash<<<dim3(Nn / TI, Hh, Bb), 256, 0, stream>>>(qws, kws, vws, ef, mw, anyB,
                                                          wep, weg, beg, aws);
    out_proj<<<dim3(1, Bb * Nn / 16), 256, 0, stream>>>(aws, wpj, bpj, out);
}

// Round 4
// 390.130 us; speedup vs baseline: 2.8544x; 1.6662x over previous
//
#include <hip/hip_runtime.h>
#include <hip/hip_bf16.h>

#define Bb 4
#define Nn 1024
#define Dd 512
#define Hh 8
#define Ee 5
#define HDd 64

typedef unsigned int u32_t;
typedef unsigned short u16_t;
typedef short s16x8 __attribute__((ext_vector_type(8)));
typedef float f32x4 __attribute__((ext_vector_type(4)));

#define MFMA(a, b, c) __builtin_amdgcn_mfma_f32_16x16x32_bf16((a), (b), (c), 0, 0, 0)

// pack fp32 -> u32: hi16 = truncated top bf16 bits, lo16 = RN bf16 of remainder.
// value ~= hi + lo with relative error ~2^-17.
__device__ __forceinline__ u32_t pack32(float x) {
    u32_t u = __float_as_uint(x);
    u32_t hi = u & 0xffff0000u;
    float rem = x - __uint_as_float(hi);
    u32_t r = __float_as_uint(rem);
    u32_t lo = (r + 0x7fffu + ((r >> 16) & 1u)) >> 16;
    return hi | (lo & 0xffffu);
}

// 8 packed u32 (as two uint4) -> hi-frag, lo-frag (bf16x8 as short8)
__device__ __forceinline__ void unpk8(uint4 A, uint4 B, s16x8& h, s16x8& l) {
    union { u16_t u[8]; s16x8 v; } H, L;
    u32_t a[8] = {A.x, A.y, A.z, A.w, B.x, B.y, B.z, B.w};
    #pragma unroll
    for (int i = 0; i < 8; i++) { H.u[i] = (u16_t)(a[i] >> 16); L.u[i] = (u16_t)(a[i] & 0xffffu); }
    h = H.v; l = L.v;
}

// split two packed u32 pairs (4 values) into hi-pair/lo-pair u32 words (2 bf16 each)
__device__ __forceinline__ void split4(uint4 A, uint2& hi, uint2& lo) {
    hi.x = (A.x >> 16) | (A.y & 0xffff0000u);
    hi.y = (A.z >> 16) | (A.w & 0xffff0000u);
    lo.x = (A.x & 0xffffu) | (A.y << 16);
    lo.y = (A.z & 0xffffu) | (A.w << 16);
}

// ---------- Kernel 0: normalize node_mask (int32 or byte-bool) -> mw[4096], anyB[4] ----------
__global__ __launch_bounds__(256) void prep_mask(const void* __restrict__ msk,
                                                 int* __restrict__ mw,
                                                 int* __restrict__ anyB) {
    __shared__ int notint;
    __shared__ int ab[Bb];
    const int tid = threadIdx.x;
    if (tid == 0) notint = 0;
    if (tid < Bb) ab[tid] = 0;
    __syncthreads();
    const u32_t* wp = (const u32_t*)msk;
    int bad = 0;
    for (int i = tid; i < 1024; i += 256) bad |= (wp[i] > 1u);
    if (bad) atomicOr(&notint, 1);
    __syncthreads();
    const int isbyte = notint;
    const unsigned char* bp = (const unsigned char*)msk;
    for (int i = tid; i < Bb * Nn; i += 256) {
        const int v = isbyte ? (bp[i] != 0) : (wp[i] != 0);
        mw[i] = v;
        if (v) atomicOr(&ab[i >> 10], 1);
    }
    __syncthreads();
    if (tid < Bb) anyB[tid] = ab[tid];
}

// ---------- Kernel A: qkv = x @ w_qkv^T via split-bf16 MFMA; packed u32 out (b,h,n,d) ----------
__global__ __launch_bounds__(256) void qkv_mfma(const float* __restrict__ x,
                                                const float* __restrict__ w,
                                                u32_t* __restrict__ q32,
                                                u32_t* __restrict__ k32,
                                                u32_t* __restrict__ v32) {
    __shared__ __align__(16) u16_t Xh[64 * 72], Xl[64 * 72];
    __shared__ __align__(16) u16_t Wh[64 * 72], Wl[64 * 72];
    const int tid = threadIdx.x;
    const int wv = tid >> 6, lane = tid & 63, lm = lane & 15, quad = lane >> 4;
    const int m0 = blockIdx.y * 64, c0 = blockIdx.x * 64;
    const int row = tid >> 2, dq = tid & 3;
    const float4* x4 = (const float4*)x;
    const float4* w4 = (const float4*)w;

    f32x4 acc[4];
    #pragma unroll
    for (int nt = 0; nt < 4; nt++) acc[nt] = {0.f, 0.f, 0.f, 0.f};

    for (int kt = 0; kt < 8; kt++) {
        __syncthreads();
        #pragma unroll
        for (int t = 0; t < 4; t++) {
            const int cc = dq * 4 + t;                    // f4-chunk within 64-k slab
            float4 xv = x4[(size_t)(m0 + row) * 128 + kt * 16 + cc];
            u32_t p0 = pack32(xv.x), p1 = pack32(xv.y), p2 = pack32(xv.z), p3 = pack32(xv.w);
            uint2 hi, lo;
            split4(make_uint4(p0, p1, p2, p3), hi, lo);
            *(uint2*)&Xh[row * 72 + cc * 4] = hi;
            *(uint2*)&Xl[row * 72 + cc * 4] = lo;
            float4 wvv = w4[(size_t)(c0 + row) * 128 + kt * 16 + cc];
            p0 = pack32(wvv.x); p1 = pack32(wvv.y); p2 = pack32(wvv.z); p3 = pack32(wvv.w);
            split4(make_uint4(p0, p1, p2, p3), hi, lo);
            *(uint2*)&Wh[row * 72 + cc * 4] = hi;
            *(uint2*)&Wl[row * 72 + cc * 4] = lo;
        }
        __syncthreads();
        s16x8 ah[2], al[2];
        #pragma unroll
        for (int ks = 0; ks < 2; ks++) {
            ah[ks] = *(const s16x8*)&Xh[(16 * wv + lm) * 72 + ks * 32 + quad * 8];
            al[ks] = *(const s16x8*)&Xl[(16 * wv + lm) * 72 + ks * 32 + quad * 8];
        }
        #pragma unroll
        for (int nt = 0; nt < 4; nt++) {
            #pragma unroll
            for (int ks = 0; ks < 2; ks++) {
                s16x8 bh = *(const s16x8*)&Wh[(16 * nt + lm) * 72 + ks * 32 + quad * 8];
                s16x8 bl = *(const s16x8*)&Wl[(16 * nt + lm) * 72 + ks * 32 + quad * 8];
                acc[nt] = MFMA(ah[ks], bh, acc[nt]);
                acc[nt] = MFMA(ah[ks], bl, acc[nt]);
                acc[nt] = MFMA(al[ks], bh, acc[nt]);
            }
        }
    }
    #pragma unroll
    for (int nt = 0; nt < 4; nt++) {
        const int c = c0 + 16 * nt + lm;
        const int s = c >> 9, hd = c & 511, h = hd >> 6, d = hd & 63;
        u32_t* dst = (s == 0) ? q32 : (s == 1) ? k32 : v32;
        #pragma unroll
        for (int r = 0; r < 4; r++) {
            const int m = m0 + 16 * wv + 4 * quad + r;
            const int b = m >> 10, n = m & (Nn - 1);
            dst[(((size_t)b * Hh + h) * Nn + n) * HDd + d] = pack32(acc[nt][r]);
        }
    }
}

// ---------- Kernel B: flash attention, split-bf16 MFMA. Block = (i-tile 64, h, b) ----------
__global__ __launch_bounds__(256) void attn_mfma(const u32_t* __restrict__ q32,
                                                 const u32_t* __restrict__ k32,
                                                 const u32_t* __restrict__ v32,
                                                 const float* __restrict__ ef,
                                                 const int* __restrict__ mw,
                                                 const int* __restrict__ anyB,
                                                 const float* __restrict__ wep,
                                                 const float* __restrict__ weg,
                                                 const float* __restrict__ beg,
                                                 float* __restrict__ aout) {
    // LDS: Q 18432 + (K alias P) 18432 + VT 22528 = 59392 B -> 2 blocks/CU
    __shared__ __align__(16) u16_t Qh[64 * 72], Ql[64 * 72];
    __shared__ __align__(16) char KP[18432];               // Kh,Kl; later aliased by Ppk
    __shared__ __align__(16) u16_t VTh[64 * 88], VTl[64 * 88];
    u16_t* Kh = (u16_t*)KP;
    u16_t* Kl = Kh + 64 * 72;
    u32_t* Ppk = (u32_t*)KP;                               // 64 x 68 u32 = 17408 B

    const int tid = threadIdx.x;
    const int wv = tid >> 6, lane = tid & 63, lm = lane & 15, quad = lane >> 4;
    const int i0 = blockIdx.x * 64;
    const int h  = blockIdx.y;
    const int b  = blockIdx.z;

    const float wp0 = wep[h*Ee+0], wp1 = wep[h*Ee+1], wp2 = wep[h*Ee+2],
                wp3 = wep[h*Ee+3], wp4 = wep[h*Ee+4];
    const float wg0 = weg[h*Ee+0], wg1 = weg[h*Ee+1], wg2 = weg[h*Ee+2],
                wg3 = weg[h*Ee+3], wg4 = weg[h*Ee+4];
    const float bgs = beg[h];

    const uint4* qg4 = (const uint4*)(q32 + (((size_t)b * Hh + h) * Nn + i0) * HDd);
    const uint4* kg4 = (const uint4*)(k32 + (((size_t)b * Hh + h) * Nn) * HDd);
    const uint4* vg4 = (const uint4*)(v32 + (((size_t)b * Hh + h) * Nn) * HDd);
    const int* mwB = mw + b * Nn;

    // ---- Q staging (once): rows = i-local ----
    {
        const int row = tid >> 2, dq = tid & 3;
        #pragma unroll
        for (int t = 0; t < 4; t++) {
            const int cc = dq * 4 + t;
            uint4 A = qg4[row * 16 + cc];
            uint2 hi, lo;
            split4(A, hi, lo);
            *(uint2*)&Qh[row * 72 + cc * 4] = hi;
            *(uint2*)&Ql[row * 72 + cc * 4] = lo;
        }
    }

    const int anyb = anyB[b];
    int rv[4];
    float m_[4], l_[4];
    f32x4 accO[4];
    #pragma unroll
    for (int r = 0; r < 4; r++) {
        rv[r] = anyb && mwB[i0 + 16 * wv + 4 * quad + r];
        m_[r] = -1e30f; l_[r] = 0.f;
    }
    #pragma unroll
    for (int dn = 0; dn < 4; dn++) accO[dn] = {0.f, 0.f, 0.f, 0.f};

    for (int jt = 0; jt < Nn / 64; jt++) {
        const int j0 = jt * 64;
        __syncthreads();   // prev-tile frag reads done (also covers Q staging on jt=0)

        // ---- K stage: [j][d] split ----
        {
            const int row = tid >> 2, dq = tid & 3;
            #pragma unroll
            for (int t = 0; t < 4; t++) {
                const int cc = dq * 4 + t;
                uint4 A = kg4[(j0 + row) * 16 + cc];
                uint2 hi, lo;
                split4(A, hi, lo);
                *(uint2*)&Kh[row * 72 + cc * 4] = hi;
                *(uint2*)&Kl[row * 72 + cc * 4] = lo;
            }
        }
        // ---- V stage transposed: VT[d][j] split ----
        {
            const int jg = tid >> 4, dc = tid & 15;
            u32_t r0[4], r1[4], r2[4], r3[4];
            uint4 A0 = vg4[(j0 + 4 * jg + 0) * 16 + dc];
            uint4 A1 = vg4[(j0 + 4 * jg + 1) * 16 + dc];
            uint4 A2 = vg4[(j0 + 4 * jg + 2) * 16 + dc];
            uint4 A3 = vg4[(j0 + 4 * jg + 3) * 16 + dc];
            r0[0]=A0.x; r0[1]=A0.y; r0[2]=A0.z; r0[3]=A0.w;
            r1[0]=A1.x; r1[1]=A1.y; r1[2]=A1.z; r1[3]=A1.w;
            r2[0]=A2.x; r2[1]=A2.y; r2[2]=A2.z; r2[3]=A2.w;
            r3[0]=A3.x; r3[1]=A3.y; r3[2]=A3.z; r3[3]=A3.w;
            #pragma unroll
            for (int c = 0; c < 4; c++) {
                const int d = 4 * dc + c;
                uint2 hi, lo;
                hi.x = (r0[c] >> 16) | (r1[c] & 0xffff0000u);
                hi.y = (r2[c] >> 16) | (r3[c] & 0xffff0000u);
                lo.x = (r0[c] & 0xffffu) | (r1[c] << 16);
                lo.y = (r2[c] & 0xffffu) | (r3[c] << 16);
                *(uint2*)&VTh[d * 88 + 4 * jg] = hi;
                *(uint2*)&VTl[d * 88 + 4 * jg] = lo;
            }
        }
        __syncthreads();

        // ---- QK^T: S[16 x 64] per wave ----
        s16x8 qh[2], ql[2];
        #pragma unroll
        for (int ks = 0; ks < 2; ks++) {
            qh[ks] = *(const s16x8*)&Qh[(16 * wv + lm) * 72 + ks * 32 + quad * 8];
            ql[ks] = *(const s16x8*)&Ql[(16 * wv + lm) * 72 + ks * 32 + quad * 8];
        }
        f32x4 S[4];
        #pragma unroll
        for (int jn = 0; jn < 4; jn++) {
            f32x4 s = {0.f, 0.f, 0.f, 0.f};
            #pragma unroll
            for (int ks = 0; ks < 2; ks++) {
                s16x8 bh = *(const s16x8*)&Kh[(16 * jn + lm) * 72 + ks * 32 + quad * 8];
                s16x8 bl = *(const s16x8*)&Kl[(16 * jn + lm) * 72 + ks * 32 + quad * 8];
                s = MFMA(qh[ks], bh, s);
                s = MFMA(qh[ks], bl, s);
                s = MFMA(ql[ks], bh, s);
            }
            S[jn] = s;
        }

        int mj[4];
        #pragma unroll
        for (int jn = 0; jn < 4; jn++) mj[jn] = mwB[j0 + 16 * jn + lm];

        // ---- gate/bias/mask + online softmax; rows = 16wv + 4quad + r, col = j0+16jn+lm ----
        float pv[4][4];
        #pragma unroll
        for (int r = 0; r < 4; r++) {
            const int i = i0 + 16 * wv + 4 * quad + r;
            float sv[4];
            #pragma unroll
            for (int jn = 0; jn < 4; jn++) {
                if (!rv[r]) {
                    sv[jn] = 0.f;
                } else if (!mj[jn]) {
                    sv[jn] = -1e30f;
                } else {
                    const float* ep = ef + ((size_t)(b * Nn + i) * Nn + (j0 + 16 * jn + lm)) * Ee;
                    const float e0 = ep[0], e1 = ep[1], e2 = ep[2], e3 = ep[3], e4 = ep[4];
                    const float bias = fmaf(e0, wp0, fmaf(e1, wp1, fmaf(e2, wp2, fmaf(e3, wp3, e4 * wp4))));
                    const float gv = fmaf(e0, wg0, fmaf(e1, wg1, fmaf(e2, wg2, fmaf(e3, wg3, fmaf(e4, wg4, bgs)))));
                    const float gate = 1.f / (1.f + __expf(-gv));
                    sv[jn] = fmaf(S[jn][r], 0.125f, gate * bias);
                }
            }
            float tmax = fmaxf(fmaxf(sv[0], sv[1]), fmaxf(sv[2], sv[3]));
            tmax = fmaxf(tmax, __shfl_xor(tmax, 1));
            tmax = fmaxf(tmax, __shfl_xor(tmax, 2));
            tmax = fmaxf(tmax, __shfl_xor(tmax, 4));
            tmax = fmaxf(tmax, __shfl_xor(tmax, 8));
            const float mnew = fmaxf(m_[r], tmax);
            const float alpha = __expf(m_[r] - mnew);
            float ps = 0.f;
            #pragma unroll
            for (int jn = 0; jn < 4; jn++) { pv[r][jn] = __expf(sv[jn] - mnew); ps += pv[r][jn]; }
            ps += __shfl_xor(ps, 1);
            ps += __shfl_xor(ps, 2);
            ps += __shfl_xor(ps, 4);
            ps += __shfl_xor(ps, 8);
            m_[r] = mnew;
            l_[r] = l_[r] * alpha + ps;
            #pragma unroll
            for (int dn = 0; dn < 4; dn++) accO[dn][r] *= alpha;
        }

        __syncthreads();   // all waves done with Kh/Kl frags; safe to overwrite with P
        #pragma unroll
        for (int r = 0; r < 4; r++)
            #pragma unroll
            for (int jn = 0; jn < 4; jn++)
                Ppk[(16 * wv + 4 * quad + r) * 68 + 16 * jn + lm] = pack32(pv[r][jn]);

        // ---- PV: reads only this wave's own P rows (16wv..16wv+15) ----
        s16x8 ph[2], pl[2];
        #pragma unroll
        for (int ks2 = 0; ks2 < 2; ks2++) {
            const int off = (16 * wv + lm) * 68 + ks2 * 32 + quad * 8;
            uint4 A = *(const uint4*)&Ppk[off];
            uint4 B = *(const uint4*)&Ppk[off + 4];
            unpk8(A, B, ph[ks2], pl[ks2]);
        }
        #pragma unroll
        for (int dn = 0; dn < 4; dn++) {
            f32x4 c = accO[dn];
            #pragma unroll
            for (int ks2 = 0; ks2 < 2; ks2++) {
                s16x8 vh = *(const s16x8*)&VTh[(16 * dn + lm) * 88 + ks2 * 32 + quad * 8];
                s16x8 vl = *(const s16x8*)&VTl[(16 * dn + lm) * 88 + ks2 * 32 + quad * 8];
                c = MFMA(ph[ks2], vh, c);
                c = MFMA(ph[ks2], vl, c);
                c = MFMA(pl[ks2], vh, c);
            }
            accO[dn] = c;
        }
    }

    #pragma unroll
    for (int r = 0; r < 4; r++) {
        const int i = i0 + 16 * wv + 4 * quad + r;
        const float inv = 1.f / l_[r];
        #pragma unroll
        for (int dn = 0; dn < 4; dn++)
            aout[(size_t)(b * Nn + i) * Dd + h * HDd + 16 * dn + lm] = accO[dn][r] * inv;
    }
}

// ---------- Kernel C: out = aout @ w_proj^T + bias via split-bf16 MFMA ----------
__global__ __launch_bounds__(256) void out_mfma(const float* __restrict__ a,
                                                const float* __restrict__ w,
                                                const float* __restrict__ bias,
                                                float* __restrict__ out) {
    __shared__ __align__(16) u16_t Xh[64 * 72], Xl[64 * 72];
    __shared__ __align__(16) u16_t Wh[64 * 72], Wl[64 * 72];
    const int tid = threadIdx.x;
    const int wv = tid >> 6, lane = tid & 63, lm = lane & 15, quad = lane >> 4;
    const int m0 = blockIdx.y * 64, c0 = blockIdx.x * 64;
    const int row = tid >> 2, dq = tid & 3;
    const float4* a4 = (const float4*)a;
    const float4* w4 = (const float4*)w;

    f32x4 acc[4];
    #pragma unroll
    for (int nt = 0; nt < 4; nt++) acc[nt] = {0.f, 0.f, 0.f, 0.f};

    for (int kt = 0; kt < 8; kt++) {
        __syncthreads();
        #pragma unroll
        for (int t = 0; t < 4; t++) {
            const int cc = dq * 4 + t;
            float4 xv = a4[(size_t)(m0 + row) * 128 + kt * 16 + cc];
            u32_t p0 = pack32(xv.x), p1 = pack32(xv.y), p2 = pack32(xv.z), p3 = pack32(xv.w);
            uint2 hi, lo;
            split4(make_uint4(p0, p1, p2, p3), hi, lo);
            *(uint2*)&Xh[row * 72 + cc * 4] = hi;
            *(uint2*)&Xl[row * 72 + cc * 4] = lo;
            float4 wvv = w4[(size_t)(c0 + row) * 128 + kt * 16 + cc];
            p0 = pack32(wvv.x); p1 = pack32(wvv.y); p2 = pack32(wvv.z); p3 = pack32(wvv.w);
            split4(make_uint4(p0, p1, p2, p3), hi, lo);
            *(uint2*)&Wh[row * 72 + cc * 4] = hi;
            *(uint2*)&Wl[row * 72 + cc * 4] = lo;
        }
        __syncthreads();
        s16x8 ah[2], al[2];
        #pragma unroll
        for (int ks = 0; ks < 2; ks++) {
            ah[ks] = *(const s16x8*)&Xh[(16 * wv + lm) * 72 + ks * 32 + quad * 8];
            al[ks] = *(const s16x8*)&Xl[(16 * wv + lm) * 72 + ks * 32 + quad * 8];
        }
        #pragma unroll
        for (int nt = 0; nt < 4; nt++) {
            #pragma unroll
            for (int ks = 0; ks < 2; ks++) {
                s16x8 bh = *(const s16x8*)&Wh[(16 * nt + lm) * 72 + ks * 32 + quad * 8];
                s16x8 bl = *(const s16x8*)&Wl[(16 * nt + lm) * 72 + ks * 32 + quad * 8];
                acc[nt] = MFMA(ah[ks], bh, acc[nt]);
                acc[nt] = MFMA(ah[ks], bl, acc[nt]);
                acc[nt] = MFMA(al[ks], bh, acc[nt]);
            }
        }
    }
    #pragma unroll
    for (int nt = 0; nt < 4; nt++) {
        const int c = c0 + 16 * nt + lm;
        const float bc = bias[c];
        #pragma unroll
        for (int r = 0; r < 4; r++) {
            const int m = m0 + 16 * wv + 4 * quad + r;
            out[(size_t)m * Dd + c] = acc[nt][r] + bc;
        }
    }
}

extern "C" void kernel_launch(void* const* d_in, const int* in_sizes, int n_in,
                              void* d_out, int out_size, void* d_ws, size_t ws_size,
                              hipStream_t stream) {
    const float* x    = (const float*)d_in[0];
    const float* ef   = (const float*)d_in[1];
    const void*  msk  = d_in[2];
    const float* wqkv = (const float*)d_in[3];
    const float* wep  = (const float*)d_in[4];
    const float* weg  = (const float*)d_in[5];
    const float* beg  = (const float*)d_in[6];
    const float* wpj  = (const float*)d_in[7];
    const float* bpj  = (const float*)d_in[8];
    float* out = (float*)d_out;

    int* mw   = (int*)d_ws;                       // 4096 ints
    int* anyB = mw + Bb * Nn;                     // 16 ints
    u32_t* q32 = (u32_t*)(anyB + 16);
    const size_t per = (size_t)Bb * Hh * Nn * HDd;  // 2,097,152
    u32_t* k32 = q32 + per;
    u32_t* v32 = k32 + per;
    float* aws = (float*)(v32 + per);             // B*N*D fp32

    prep_mask<<<1, 256, 0, stream>>>(msk, mw, anyB);
    qkv_mfma<<<dim3(24, 64), 256, 0, stream>>>(x, wqkv, q32, k32, v32);
    attn_mfma<<<dim3(Nn / 64, Hh, Bb), 256, 0, stream>>>(q32, k32, v32, ef, mw, anyB,
                                                         wep, weg, beg, aws);
    out_mfma<<<dim3(8, 64), 256, 0, stream>>>(aws, wpj, bpj, out);
}